// Round 1
// 235.368 us; speedup vs baseline: 1.0034x; 1.0034x over previous
//
#include <hip/hip_runtime.h>
#include <hip/hip_fp16.h>

// Strategy: the whole network is a pointwise function code = F(sigma),
// sigma in [0.5, 2.5).  Build a G_TAB-point lookup table of F (exact f32
// network eval) and linearly interpolate per pixel.  Table stored as
// half2 {F[i],F[i+1]} so one dword fetch gives both lerp endpoints.
//
// R4: (a) build rewritten barrier-free: one wave per table entry, full
// matvecs via __shfl broadcast of the activation vector (removes ~18
// barrier phases + all partial-sum LDS round trips; same FLOPs/wave);
// (b) interp rewritten register-only: each thread owns 4 consecutive
// pixels (a v-quad) and stores global_store_dwordx4 -> every wave store
// instruction covers 1 KB contiguous HBM (vs 256 B before); table rows
// gathered as 16B chunks from L2-resident 512 KB table; no LDS.

#define G_TAB 2048
#define NK 441           // 21*21
#define UV 65536         // 256*256

// ws layout (float units)
#define OFF_TABLE 0                        // half2[2048][64] = 131072 floats
#define OFF_PET   131072                   // [441][64]
#define OFF_WVT   (OFF_PET + NK*64)        // [2][64][64]
#define OFF_OUTT  (OFF_WVT + 2*64*64)      // [2][64][64]
#define OFF_FF1T  (OFF_OUTT + 2*64*64)     // [2][64][256]
#define OFF_FF2T  (OFF_FF1T + 2*64*256)    // [2][256][64]
#define OFF_H1T   (OFF_FF2T + 2*256*64)    // [64][64]
#define OFF_H2T   (OFF_H1T + 64*64)        // [64][64]

#define PREP_N (28224 + 8192 + 8192 + 32768 + 32768 + 4096 + 4096)  // 118336

typedef float f32x4 __attribute__((ext_vector_type(4)));
typedef unsigned int u32x4 __attribute__((ext_vector_type(4)));

// ---------------- prep: transpose weights to [k][out] for coalesced matvec ----

__global__ __launch_bounds__(256) void prep_kernel(
    const float* __restrict__ pe_w, const float* __restrict__ in_w,
    const float* __restrict__ out_w, const float* __restrict__ ff1_w,
    const float* __restrict__ ff2_w, const float* __restrict__ h1_w,
    const float* __restrict__ h2_w, float* __restrict__ ws) {
  int t = blockIdx.x * 256 + threadIdx.x;
  if (t < 28224) {                       // peT[idx][e] = pe_w[e][idx]
    int e = t & 63, idx = t >> 6;
    ws[OFF_PET + t] = pe_w[e * 441 + idx];
    return;
  }
  t -= 28224;
  if (t < 8192) {                        // wvT[l][k][a] = in_w[l][128+a][k]
    int a = t & 63, k = (t >> 6) & 63, l = t >> 12;
    ws[OFF_WVT + t] = in_w[l * 12288 + (128 + a) * 64 + k];
    return;
  }
  t -= 8192;
  if (t < 8192) {                        // outT[l][a][e] = out_w[l][e][a]
    int e = t & 63, a = (t >> 6) & 63, l = t >> 12;
    ws[OFF_OUTT + t] = out_w[(l * 64 + e) * 64 + a];
    return;
  }
  t -= 8192;
  if (t < 32768) {                       // ff1T[l][k][a] = ff1_w[l][a][k]
    int a = t & 255, k = (t >> 8) & 63, l = t >> 14;
    ws[OFF_FF1T + t] = ff1_w[(l * 256 + a) * 64 + k];
    return;
  }
  t -= 32768;
  if (t < 32768) {                       // ff2T[l][k][e] = ff2_w[l][e][k]
    int e = t & 63, k = (t >> 6) & 255, l = t >> 14;
    ws[OFF_FF2T + t] = ff2_w[(l * 64 + e) * 256 + k];
    return;
  }
  t -= 32768;
  if (t < 4096) {                        // h1T[k][a] = h1_w[a][k]
    int a = t & 63, k = t >> 6;
    ws[OFF_H1T + t] = h1_w[a * 64 + k];
    return;
  }
  t -= 4096;
  if (t < 4096) {                        // h2T[a][c] = h2_w[c][a]
    int c = t & 63, a = t >> 6;
    ws[OFF_H2T + t] = h2_w[c * 64 + a];
    return;
  }
}

// ---------------- build: one wave per table entry, barrier-free ---------------

__device__ __forceinline__ float lnorm(float t, float g, float b) {
  float s1 = t;
#pragma unroll
  for (int o = 1; o < 64; o <<= 1) s1 += __shfl_xor(s1, o, 64);
  float d = t - s1 * (1.0f / 64.0f);
  float s2 = d * d;
#pragma unroll
  for (int o = 1; o < 64; o <<= 1) s2 += __shfl_xor(s2, o, 64);
  return d * rsqrtf(s2 * (1.0f / 64.0f) + 1e-5f) * g + b;
}

__global__ __launch_bounds__(256) void build_table_kernel(
    const float* __restrict__ pe_b, const float* __restrict__ in_b,
    const float* __restrict__ out_b, const float* __restrict__ ff1_b,
    const float* __restrict__ ff2_b, const float* __restrict__ ln1_g,
    const float* __restrict__ ln1_b, const float* __restrict__ ln2_g,
    const float* __restrict__ ln2_b, const float* __restrict__ h1_b,
    const float* __restrict__ h2_b, float* __restrict__ ws) {
  __shared__ float kern_s[4][NK];   // per-wave gaussian kernel (wave-private)
  const int tid = threadIdx.x;
  const int wave = tid >> 6, lane = tid & 63;
  const int g = blockIdx.x * 4 + wave;   // this wave's table entry

  const float sgv = 0.5f + 2.0f * (float)g / (float)(G_TAB - 1);
  const float inv2s2 = 1.0f / (2.0f * sgv * sgv);

  // Gaussian kernel: lane-split eval into LDS + wave sum.
  float* ks = kern_s[wave];
  float s = 0.0f;
  for (int idx = lane; idx < NK; idx += 64) {
    int q = idx / 21;
    int di = q - 10, dj = idx - q * 21 - 10;
    float kv = __expf(-(float)(di * di + dj * dj) * inv2s2);
    ks[idx] = kv;
    s += kv;
  }
#pragma unroll
  for (int o = 1; o < 64; o <<= 1) s += __shfl_xor(s, o, 64);
  __syncthreads();  // lgkm drain so all lanes see the wave's LDS writes

  // patch embed: x[lane] = (sum_idx kv*peT[idx][lane]) / s + pe_b[lane]
  const float* peT = ws + OFF_PET;
  float acc0 = 0.0f, acc1 = 0.0f;
  for (int idx = 0; idx + 1 < NK; idx += 2) {
    acc0 = fmaf(ks[idx], peT[idx * 64 + lane], acc0);
    acc1 = fmaf(ks[idx + 1], peT[(idx + 1) * 64 + lane], acc1);
  }
  acc0 = fmaf(ks[NK - 1], peT[(NK - 1) * 64 + lane], acc0);
  float x = fmaf(acc0 + acc1, 1.0f / s, pe_b[lane]);

  for (int l = 0; l < 2; l++) {
    const float* Wv = ws + OFF_WVT + l * 4096;
    const float* Wo = ws + OFF_OUTT + l * 4096;
    const float* F1 = ws + OFF_FF1T + l * 16384;
    const float* F2 = ws + OFF_FF2T + l * 16384;

    // v-proj (64x64): shfl-broadcast x
    float a1 = 0.0f;
#pragma unroll 16
    for (int k = 0; k < 64; k++)
      a1 = fmaf(__shfl(x, k, 64), Wv[k * 64 + lane], a1);
    float v = a1 + in_b[l * 192 + 128 + lane];

    // out-proj (64x64)
    float a2 = 0.0f;
#pragma unroll 16
    for (int k = 0; k < 64; k++)
      a2 = fmaf(__shfl(v, k, 64), Wo[k * 64 + lane], a2);
    float t1 = x + a2 + out_b[l * 64 + lane];
    x = lnorm(t1, ln1_g[l * 64 + lane], ln1_b[l * 64 + lane]);

    // ffn1 (64->256): lane owns hidden units lane+64j
    float h0 = 0.0f, h1v = 0.0f, h2v = 0.0f, h3v = 0.0f;
#pragma unroll 8
    for (int k = 0; k < 64; k++) {
      float xk = __shfl(x, k, 64);
      h0  = fmaf(xk, F1[k * 256 + lane      ], h0);
      h1v = fmaf(xk, F1[k * 256 + lane +  64], h1v);
      h2v = fmaf(xk, F1[k * 256 + lane + 128], h2v);
      h3v = fmaf(xk, F1[k * 256 + lane + 192], h3v);
    }
    h0  = fmaxf(h0  + ff1_b[l * 256 + lane      ], 0.0f);
    h1v = fmaxf(h1v + ff1_b[l * 256 + lane +  64], 0.0f);
    h2v = fmaxf(h2v + ff1_b[l * 256 + lane + 128], 0.0f);
    h3v = fmaxf(h3v + ff1_b[l * 256 + lane + 192], 0.0f);

    // ffn2 (256->64): 4 independent 64-chains
    float b0 = 0.0f, b1 = 0.0f, b2 = 0.0f, b3 = 0.0f;
#pragma unroll 16
    for (int k = 0; k < 64; k++) {
      b0 = fmaf(__shfl(h0,  k, 64), F2[(k      ) * 64 + lane], b0);
      b1 = fmaf(__shfl(h1v, k, 64), F2[(k +  64) * 64 + lane], b1);
      b2 = fmaf(__shfl(h2v, k, 64), F2[(k + 128) * 64 + lane], b2);
      b3 = fmaf(__shfl(h3v, k, 64), F2[(k + 192) * 64 + lane], b3);
    }
    float t2 = x + ((b0 + b1) + (b2 + b3)) + ff2_b[l * 64 + lane];
    x = lnorm(t2, ln2_g[l * 64 + lane], ln2_b[l * 64 + lane]);
  }

  // head layer 1 + leaky relu
  const float* H1 = ws + OFF_H1T;
  float a4 = 0.0f;
#pragma unroll 16
  for (int k = 0; k < 64; k++)
    a4 = fmaf(__shfl(x, k, 64), H1[k * 64 + lane], a4);
  float hh = a4 + h1_b[lane];
  hh = hh >= 0.0f ? hh : 0.1f * hh;

  // head layer 2 + table write (half, interleaved {F[i],F[i+1]})
  const float* H2 = ws + OFF_H2T;
  float a5 = 0.0f;
#pragma unroll 16
  for (int k = 0; k < 64; k++)
    a5 = fmaf(__shfl(hh, k, 64), H2[k * 64 + lane], a5);
  float c = a5 + h2_b[lane];

  __half hv = __float2half(c);
  __half* tabh = (__half*)ws;
  tabh[(g * 64 + lane) * 2] = hv;                       // slot0 of entry g
  if (g > 0) tabh[((g - 1) * 64 + lane) * 2 + 1] = hv;  // slot1 of entry g-1
  // entry G_TAB-1 slot1 never written, never read (i0 clamped to G_TAB-2)
}

// ---------------- interp: thread = v-quad, register-only, 1KB dwordx4 stores --

__device__ __forceinline__ float2 h2f2(unsigned int w) {
  __half2 h;
  __builtin_memcpy(&h, &w, 4);
  return __half22float2(h);
}

__global__ __launch_bounds__(256) void interp_kernel(
    const float* __restrict__ sigma, const float* __restrict__ ws,
    float* __restrict__ out, int npix) {
  int t = blockIdx.x * 256 + threadIdx.x;
  int p0 = t * 4;                      // first pixel of this thread's v-quad
  if (p0 >= npix) return;

  f32x4 sg = *(const f32x4*)(sigma + p0);

  float t0 = fmaxf((sg.x - 0.5f) * ((float)(G_TAB - 1) * 0.5f), 0.0f);
  float t1 = fmaxf((sg.y - 0.5f) * ((float)(G_TAB - 1) * 0.5f), 0.0f);
  float t2 = fmaxf((sg.z - 0.5f) * ((float)(G_TAB - 1) * 0.5f), 0.0f);
  float t3 = fmaxf((sg.w - 0.5f) * ((float)(G_TAB - 1) * 0.5f), 0.0f);
  int i0 = (int)t0; if (i0 > G_TAB - 2) i0 = G_TAB - 2;
  int i1 = (int)t1; if (i1 > G_TAB - 2) i1 = G_TAB - 2;
  int i2 = (int)t2; if (i2 > G_TAB - 2) i2 = G_TAB - 2;
  int i3 = (int)t3; if (i3 > G_TAB - 2) i3 = G_TAB - 2;
  float f0 = t0 - (float)i0, f1 = t1 - (float)i1;
  float f2 = t2 - (float)i2, f3 = t3 - (float)i3;

  const u32x4* __restrict__ tabq = (const u32x4*)ws;  // 16 u32x4 per entry row
  int rb0 = i0 * 16, rb1 = i1 * 16, rb2 = i2 * 16, rb3 = i3 * 16;

  int bimg = p0 >> 16;
  int rr = p0 & (UV - 1);
  float* obase = out + (size_t)bimg * (64 * UV) + rr;

#pragma unroll 2
  for (int cq = 0; cq < 16; cq++) {
    u32x4 q0 = tabq[rb0 + cq];   // 4 channels x half2{F[i],F[i+1]} per pixel
    u32x4 q1 = tabq[rb1 + cq];
    u32x4 q2 = tabq[rb2 + cq];
    u32x4 q3 = tabq[rb3 + cq];
#pragma unroll
    for (int cc = 0; cc < 4; cc++) {
      float2 a0 = h2f2(q0[cc]);
      float2 a1 = h2f2(q1[cc]);
      float2 a2 = h2f2(q2[cc]);
      float2 a3 = h2f2(q3[cc]);
      f32x4 v;
      v.x = fmaf(f0, a0.y - a0.x, a0.x);
      v.y = fmaf(f1, a1.y - a1.x, a1.x);
      v.z = fmaf(f2, a2.y - a2.x, a2.x);
      v.w = fmaf(f3, a3.y - a3.x, a3.x);
      // wave covers one full 256-float v-row per instruction: 1KB contiguous
      __builtin_nontemporal_store(v,
          (f32x4*)(obase + (size_t)(cq * 4 + cc) * UV));
    }
  }
}

extern "C" void kernel_launch(void* const* d_in, const int* in_sizes, int n_in,
                              void* d_out, int out_size, void* d_ws, size_t ws_size,
                              hipStream_t stream) {
  const float* sigma = (const float*)d_in[0];
  const float* pe_w  = (const float*)d_in[1];
  const float* pe_b  = (const float*)d_in[2];
  const float* in_w  = (const float*)d_in[3];
  const float* in_b  = (const float*)d_in[4];
  const float* out_w = (const float*)d_in[5];
  const float* out_b = (const float*)d_in[6];
  const float* ff1_w = (const float*)d_in[7];
  const float* ff1_b = (const float*)d_in[8];
  const float* ff2_w = (const float*)d_in[9];
  const float* ff2_b = (const float*)d_in[10];
  const float* ln1_g = (const float*)d_in[11];
  const float* ln1_b = (const float*)d_in[12];
  const float* ln2_g = (const float*)d_in[13];
  const float* ln2_b = (const float*)d_in[14];
  const float* h1_w  = (const float*)d_in[15];
  const float* h1_b  = (const float*)d_in[16];
  const float* h2_w  = (const float*)d_in[17];
  const float* h2_b  = (const float*)d_in[18];
  float* ws  = (float*)d_ws;
  float* out = (float*)d_out;
  int npix = in_sizes[0];

  prep_kernel<<<(PREP_N + 255) / 256, 256, 0, stream>>>(
      pe_w, in_w, out_w, ff1_w, ff2_w, h1_w, h2_w, ws);
  build_table_kernel<<<G_TAB / 4, 256, 0, stream>>>(
      pe_b, in_b, out_b, ff1_b, ff2_b, ln1_g, ln1_b, ln2_g, ln2_b,
      h1_b, h2_b, ws);
  int nthr = npix >> 2;
  interp_kernel<<<(nthr + 255) / 256, 256, 0, stream>>>(sigma, ws, out, npix);
}